// Round 1
// baseline (235.189 us; speedup 1.0000x reference)
//
#include <hip/hip_runtime.h>
#include <hip/hip_bf16.h>

// Problem constants (reference: B=2048, F=512, U=512, G=64, REG_STRENGTH=1.0)
#define B_SZ 2048
#define F_SZ 512
#define U_SZ 512
#define G_SZ 64
#define REG_STRENGTH 1.0f

// GEMM tiling
#define BM 32     // rows (samples) per block tile
#define BN 128    // u-columns per block tile
#define BK 32     // k-chunk
#define NTILES (U_SZ / BN)   // 4

// Workspace layout (floats/ints):
//  wsf[0] = w-loss accumulator (atomicAdd target), wsf[1] = b-loss (weighted)
//  counts[64], rowstart[64], order[2048]
// total = (2 + 64 + 64 + 2048) * 4 = 8712 bytes

// ---------------------------------------------------------------------------
// Kernel A: single block. Histogram gid -> counts, prefix sum -> rowstart,
// scatter sample indices -> order. Also computes weighted bias reg loss and
// zeroes the w-loss accumulator.
// ---------------------------------------------------------------------------
__global__ __launch_bounds__(256) void prep_kernel(
    const int* __restrict__ gid, const float* __restrict__ b_mu,
    const float* __restrict__ b0_mu, float* __restrict__ wsf,
    int* __restrict__ counts, int* __restrict__ rowstart,
    int* __restrict__ order) {
  __shared__ int cnt_s[G_SZ];
  __shared__ int cur_s[G_SZ];
  __shared__ float red[256];
  const int tid = threadIdx.x;

  if (tid < G_SZ) cnt_s[tid] = 0;
  if (tid == 0) wsf[0] = 0.0f;
  __syncthreads();

  for (int b = tid; b < B_SZ; b += 256) atomicAdd(&cnt_s[gid[b]], 1);
  __syncthreads();

  if (tid == 0) {
    int run = 0;
    for (int g = 0; g < G_SZ; ++g) { cur_s[g] = run; run += cnt_s[g]; }
  }
  __syncthreads();

  if (tid < G_SZ) { counts[tid] = cnt_s[tid]; rowstart[tid] = cur_s[tid]; }
  __syncthreads();

  for (int b = tid; b < B_SZ; b += 256) {
    int pos = atomicAdd(&cur_s[gid[b]], 1);
    order[pos] = b;
  }

  // Weighted bias reg loss: sum_g counts[g] * sum_u (b_mu[g,u]-b0[u])^2
  float p = 0.0f;
  for (int i = tid; i < G_SZ * U_SZ; i += 256) {
    int g = i >> 9;  // /512
    float d = b_mu[i] - b0_mu[i & (U_SZ - 1)];
    p += (float)cnt_s[g] * d * d;
  }
  red[tid] = p;
  __syncthreads();
  for (int s = 128; s > 0; s >>= 1) {
    if (tid < s) red[tid] += red[tid + s];
    __syncthreads();
  }
  if (tid == 0) wsf[1] = red[0];
}

// ---------------------------------------------------------------------------
// Kernel B: grouped GEMM, block = (u-tile, group). Out_rows = X_rows @ Wg^T + b.
// Fuses sum((Wg - W0)^2) into W staging (first row-chunk only), weighted by
// count, atomicAdd into wsf[0].
// ---------------------------------------------------------------------------
__global__ __launch_bounds__(256) void gemm_kernel(
    const float* __restrict__ x, const float* __restrict__ w_mu,
    const float* __restrict__ b_mu, const float* __restrict__ w0_mu,
    float* __restrict__ out, float* __restrict__ wsf,
    const int* __restrict__ counts, const int* __restrict__ rowstart,
    const int* __restrict__ order) {
  const int g = blockIdx.y;
  const int n0 = blockIdx.x * BN;
  const int cnt = counts[g];
  if (cnt == 0) return;  // uniform per block; no reg contribution (weight 0)
  const int rs = rowstart[g];
  const int tid = threadIdx.x;

  // Staging mapping: m/u0 = tid/8 (0..31), kq = tid%8 (k-quad)
  const int sm = tid >> 3;
  const int kq = tid & 7;
  const int kb = kq * 4;
  // Compute mapping: tn = tid%32 (u quad), tmc = tid/32 (row quad)
  const int tn = tid & 31;
  const int tmc = tid >> 5;

  __shared__ __align__(16) float Xs[BK][BM + 4];    // stride 36 words (16B-aligned rows)
  __shared__ __align__(16) float Ws[BK][BN + 4];    // stride 132 words (16B-aligned rows)

  const float* __restrict__ Wg = w_mu + (size_t)g * U_SZ * F_SZ;
  float regp = 0.0f;

  for (int r0 = 0; r0 < cnt; r0 += BM) {
    float acc[4][4] = {};
    int rr = r0 + sm;
    if (rr >= cnt) rr = cnt - 1;  // clamp; results discarded at store
    const float* __restrict__ xrow = x + (size_t)order[rs + rr] * F_SZ;

    for (int kc = 0; kc < F_SZ; kc += BK) {
      __syncthreads();  // protect LDS from previous chunk's readers
      // --- stage X tile (transposed): Xs[k][m] ---
      const float4 xv4 = *(const float4*)(xrow + kc + kb);
      Xs[kb + 0][sm] = xv4.x;
      Xs[kb + 1][sm] = xv4.y;
      Xs[kb + 2][sm] = xv4.z;
      Xs[kb + 3][sm] = xv4.w;
      // --- stage W tile (transposed): Ws[k][u], fused reg-loss on pass 1 ---
#pragma unroll
      for (int j = 0; j < 4; ++j) {
        const int u = sm + 32 * j;  // 0..127
        const float4 wv4 = *(const float4*)(Wg + (size_t)(n0 + u) * F_SZ + kc + kb);
        Ws[kb + 0][u] = wv4.x;
        Ws[kb + 1][u] = wv4.y;
        Ws[kb + 2][u] = wv4.z;
        Ws[kb + 3][u] = wv4.w;
        if (r0 == 0) {
          const float4 w0v = *(const float4*)(w0_mu + (size_t)(n0 + u) * F_SZ + kc + kb);
          float dx = wv4.x - w0v.x, dy = wv4.y - w0v.y;
          float dz = wv4.z - w0v.z, dw = wv4.w - w0v.w;
          regp += dx * dx + dy * dy + dz * dz + dw * dw;
        }
      }
      __syncthreads();
      // --- compute: 4x4 register tile over BK ---
#pragma unroll
      for (int kk = 0; kk < BK; ++kk) {
        const float4 av = *(const float4*)&Xs[kk][tmc * 4];
        const float4 bv = *(const float4*)&Ws[kk][tn * 4];
        const float a[4] = {av.x, av.y, av.z, av.w};
        const float b[4] = {bv.x, bv.y, bv.z, bv.w};
#pragma unroll
        for (int i = 0; i < 4; ++i)
#pragma unroll
          for (int j = 0; j < 4; ++j) acc[i][j] += a[i] * b[j];
      }
    }

    // --- epilogue: add bias, scatter rows to original batch indices ---
    const float4 bias = *(const float4*)(b_mu + (g << 9) + n0 + tn * 4);
#pragma unroll
    for (int i = 0; i < 4; ++i) {
      const int r = r0 + tmc * 4 + i;
      if (r < cnt) {
        float4 o;
        o.x = acc[i][0] + bias.x;
        o.y = acc[i][1] + bias.y;
        o.z = acc[i][2] + bias.z;
        o.w = acc[i][3] + bias.w;
        *(float4*)(out + (size_t)order[rs + r] * U_SZ + n0 + tn * 4) = o;
      }
    }
  }

  // --- block-reduce fused reg-loss partial, weight by count, one atomic ---
  __syncthreads();
  float* red = &Xs[0][0];  // reuse LDS (>= 256 floats)
  red[tid] = regp;
  __syncthreads();
  for (int s = 128; s > 0; s >>= 1) {
    if (tid < s) red[tid] += red[tid + s];
    __syncthreads();
  }
  if (tid == 0) atomicAdd(wsf, (float)cnt * red[0]);
}

// ---------------------------------------------------------------------------
// Kernel C: finalize scalar reg loss into d_out[B*U].
// ---------------------------------------------------------------------------
__global__ void finalize_kernel(const float* __restrict__ wsf,
                                float* __restrict__ out) {
  out[(size_t)B_SZ * U_SZ] = REG_STRENGTH * (wsf[0] + wsf[1]);
}

extern "C" void kernel_launch(void* const* d_in, const int* in_sizes, int n_in,
                              void* d_out, int out_size, void* d_ws, size_t ws_size,
                              hipStream_t stream) {
  const float* x     = (const float*)d_in[0];
  const int*   gid   = (const int*)d_in[1];
  const float* w_mu  = (const float*)d_in[2];
  const float* b_mu  = (const float*)d_in[3];
  const float* w0_mu = (const float*)d_in[4];
  const float* b0_mu = (const float*)d_in[5];
  float* out = (float*)d_out;

  float* wsf     = (float*)d_ws;
  int*   counts  = (int*)d_ws + 2;
  int*   rowstart= (int*)d_ws + 2 + G_SZ;
  int*   order   = (int*)d_ws + 2 + 2 * G_SZ;

  prep_kernel<<<1, 256, 0, stream>>>(gid, b_mu, b0_mu, wsf, counts, rowstart, order);
  gemm_kernel<<<dim3(NTILES, G_SZ), 256, 0, stream>>>(
      x, w_mu, b_mu, w0_mu, out, wsf, counts, rowstart, order);
  finalize_kernel<<<1, 1, 0, stream>>>(wsf, out);
}

// Round 2
// 141.966 us; speedup vs baseline: 1.6567x; 1.6567x over previous
//
#include <hip/hip_runtime.h>
#include <hip/hip_bf16.h>

// Problem constants (reference: B=2048, F=512, U=512, G=64, REG_STRENGTH=1.0)
#define B_SZ 2048
#define F_SZ 512
#define U_SZ 512
#define G_SZ 64
#define REG_STRENGTH 1.0f

// GEMM tiling: block tile BM x BN, K-chunk BK, 128 threads (2 waves),
// per-thread 4x4 register tile. Grid (8 u-tiles, 64 groups, ZSPLIT row-chunks).
#define BM 32
#define BN 64
#define BK 32
#define ZSPLIT 2
#define NTILES (U_SZ / BN)   // 8
#define THREADS 128

// Workspace: wsf[0] = reg-loss accumulator; counts[64]; rowstart[64]; order[2048]

// ---------------------------------------------------------------------------
// Kernel A: histogram gid -> counts, prefix sum -> rowstart, scatter -> order.
// 1024 threads so the global loads pipeline (2 elements/thread).
// ---------------------------------------------------------------------------
__global__ __launch_bounds__(1024) void prep_kernel(
    const int* __restrict__ gid, float* __restrict__ wsf,
    int* __restrict__ counts, int* __restrict__ rowstart,
    int* __restrict__ order) {
  __shared__ int cnt_s[G_SZ];
  __shared__ int cur_s[G_SZ];
  const int tid = threadIdx.x;

  if (tid < G_SZ) cnt_s[tid] = 0;
  if (tid == 0) wsf[0] = 0.0f;
  __syncthreads();

  for (int b = tid; b < B_SZ; b += 1024) atomicAdd(&cnt_s[gid[b]], 1);
  __syncthreads();

  if (tid == 0) {
    int run = 0;
    for (int g = 0; g < G_SZ; ++g) { cur_s[g] = run; run += cnt_s[g]; }
  }
  __syncthreads();

  if (tid < G_SZ) { counts[tid] = cnt_s[tid]; rowstart[tid] = cur_s[tid]; }
  __syncthreads();  // snapshot rowstart before scatter mutates cur_s

  for (int b = tid; b < B_SZ; b += 1024) {
    int pos = atomicAdd(&cur_s[gid[b]], 1);
    order[pos] = b;
  }
}

// ---------------------------------------------------------------------------
// Kernel B: grouped GEMM with register-double-buffered staging.
// block = (u-tile x, group g, row-chunk z). Out = X_rows @ Wg^T + b.
// Fuses sum((Wg-W0)^2) (z==0, first r0 pass) and the b-loss (x==0 && z==0),
// both weighted by cnt via one block reduction + one atomicAdd.
// ---------------------------------------------------------------------------
__global__ __launch_bounds__(THREADS) void gemm_kernel(
    const float* __restrict__ x, const float* __restrict__ w_mu,
    const float* __restrict__ b_mu, const float* __restrict__ w0_mu,
    const float* __restrict__ b0_mu, float* __restrict__ out,
    float* __restrict__ wsf, const int* __restrict__ counts,
    const int* __restrict__ rowstart, const int* __restrict__ order) {
  const int g = blockIdx.y;
  const int cnt = counts[g];
  if (cnt == 0) return;  // weight = cnt = 0 -> no output rows, no reg contrib
  const int z = blockIdx.z;
  const int n0 = blockIdx.x * BN;
  const int rs = rowstart[g];
  const int tid = threadIdx.x;

  // compute mapping: 4x4 tile; cols n0 + tn*4..+3, rows r0 + tmc*4..+3
  const int tn = tid & 15;   // 16 * 4 = 64 cols
  const int tmc = tid >> 4;  // 8 * 4 = 32 rows
  // staging mapping (float4-granular, coalesced): f4 index i -> row i>>3, kq i&7
  const int sr = tid >> 3;   // 0..15
  const int skq = tid & 7;   // 0..7
  const int kb = skq * 4;

  __shared__ __align__(16) float Xs[BK][BM + 4];  // stride 36 words
  __shared__ __align__(16) float Ws[BK][BN + 4];  // stride 68 words

  const float* __restrict__ Wg = w_mu + (size_t)g * (U_SZ * F_SZ);
  const bool do_reg = (z == 0);
  float regp = 0.0f;

  // fused bias reg loss: one block per group (x==0, z==0), 4 elems/thread
  if (do_reg && blockIdx.x == 0) {
    const float4 bm4 = *(const float4*)(b_mu + (g << 9) + tid * 4);
    const float4 b04 = *(const float4*)(b0_mu + tid * 4);
    float dx = bm4.x - b04.x, dy = bm4.y - b04.y;
    float dz = bm4.z - b04.z, dw = bm4.w - b04.w;
    regp += dx * dx + dy * dy + dz * dz + dw * dw;
  }

  bool first_pass = true;
  for (int r0 = z * BM; r0 < cnt; r0 += BM * ZSPLIT) {
    float acc[4][4] = {};
    int rA = r0 + sr;      if (rA >= cnt) rA = cnt - 1;  // clamp; not stored
    int rB = r0 + sr + 16; if (rB >= cnt) rB = cnt - 1;
    const float* __restrict__ xrowA = x + (size_t)order[rs + rA] * F_SZ;
    const float* __restrict__ xrowB = x + (size_t)order[rs + rB] * F_SZ;

    // prefetch chunk 0 into registers
    float4 xpA = *(const float4*)(xrowA + kb);
    float4 xpB = *(const float4*)(xrowB + kb);
    float4 wp[4];
#pragma unroll
    for (int m = 0; m < 4; ++m)
      wp[m] = *(const float4*)(Wg + (size_t)(n0 + sr + 16 * m) * F_SZ + kb);

    for (int kc = 0; kc < F_SZ; kc += BK) {
      __syncthreads();  // previous chunk's readers done
      // ---- store prefetched registers into LDS (transposed: [k][m/u]) ----
      Xs[kb + 0][sr] = xpA.x; Xs[kb + 1][sr] = xpA.y;
      Xs[kb + 2][sr] = xpA.z; Xs[kb + 3][sr] = xpA.w;
      Xs[kb + 0][sr + 16] = xpB.x; Xs[kb + 1][sr + 16] = xpB.y;
      Xs[kb + 2][sr + 16] = xpB.z; Xs[kb + 3][sr + 16] = xpB.w;
#pragma unroll
      for (int m = 0; m < 4; ++m) {
        const int u = sr + 16 * m;
        Ws[kb + 0][u] = wp[m].x; Ws[kb + 1][u] = wp[m].y;
        Ws[kb + 2][u] = wp[m].z; Ws[kb + 3][u] = wp[m].w;
      }
      // ---- fused W reg loss (uses wp before it is overwritten) ----
      if (do_reg && first_pass) {
#pragma unroll
        for (int m = 0; m < 4; ++m) {
          const float4 w04 = *(const float4*)(
              w0_mu + (size_t)(n0 + sr + 16 * m) * F_SZ + kc + kb);
          float dx = wp[m].x - w04.x, dy = wp[m].y - w04.y;
          float dz = wp[m].z - w04.z, dw = wp[m].w - w04.w;
          regp += dx * dx + dy * dy + dz * dz + dw * dw;
        }
      }
      __syncthreads();
      // ---- issue next chunk's global loads; they land during compute ----
      if (kc + BK < F_SZ) {
        const int ko = kc + BK + kb;
        xpA = *(const float4*)(xrowA + ko);
        xpB = *(const float4*)(xrowB + ko);
#pragma unroll
        for (int m = 0; m < 4; ++m)
          wp[m] = *(const float4*)(Wg + (size_t)(n0 + sr + 16 * m) * F_SZ + ko);
      }
      // ---- compute: 4x4 register tile over BK ----
#pragma unroll
      for (int kk = 0; kk < BK; ++kk) {
        const float4 av = *(const float4*)&Xs[kk][tmc * 4];
        const float4 bv = *(const float4*)&Ws[kk][tn * 4];
        const float a[4] = {av.x, av.y, av.z, av.w};
        const float b[4] = {bv.x, bv.y, bv.z, bv.w};
#pragma unroll
        for (int i = 0; i < 4; ++i)
#pragma unroll
          for (int j = 0; j < 4; ++j) acc[i][j] += a[i] * b[j];
      }
    }

    // ---- epilogue: bias + scatter to original batch rows ----
    const float4 bias = *(const float4*)(b_mu + (g << 9) + n0 + tn * 4);
#pragma unroll
    for (int i = 0; i < 4; ++i) {
      const int r = r0 + tmc * 4 + i;
      if (r < cnt) {
        float4 o;
        o.x = acc[i][0] + bias.x;
        o.y = acc[i][1] + bias.y;
        o.z = acc[i][2] + bias.z;
        o.w = acc[i][3] + bias.w;
        *(float4*)(out + (size_t)order[rs + r] * U_SZ + n0 + tn * 4) = o;
      }
    }
    first_pass = false;
  }

  // ---- block-reduce reg partials, weight by cnt, one atomic (z==0 only) ----
  if (do_reg) {
    __syncthreads();
    float* red = &Xs[0][0];  // reuse LDS (>=128 floats)
    red[tid] = regp;
    __syncthreads();
    for (int s = 64; s > 0; s >>= 1) {
      if (tid < s) red[tid] += red[tid + s];
      __syncthreads();
    }
    if (tid == 0) atomicAdd(wsf, (float)cnt * red[0]);
  }
}

// ---------------------------------------------------------------------------
// Kernel C: finalize scalar reg loss into d_out[B*U].
// ---------------------------------------------------------------------------
__global__ void finalize_kernel(const float* __restrict__ wsf,
                                float* __restrict__ out) {
  out[(size_t)B_SZ * U_SZ] = REG_STRENGTH * wsf[0];
}

extern "C" void kernel_launch(void* const* d_in, const int* in_sizes, int n_in,
                              void* d_out, int out_size, void* d_ws, size_t ws_size,
                              hipStream_t stream) {
  const float* x     = (const float*)d_in[0];
  const int*   gid   = (const int*)d_in[1];
  const float* w_mu  = (const float*)d_in[2];
  const float* b_mu  = (const float*)d_in[3];
  const float* w0_mu = (const float*)d_in[4];
  const float* b0_mu = (const float*)d_in[5];
  float* out = (float*)d_out;

  float* wsf      = (float*)d_ws;
  int*   counts   = (int*)d_ws + 2;
  int*   rowstart = (int*)d_ws + 2 + G_SZ;
  int*   order    = (int*)d_ws + 2 + 2 * G_SZ;

  prep_kernel<<<1, 1024, 0, stream>>>(gid, wsf, counts, rowstart, order);
  gemm_kernel<<<dim3(NTILES, G_SZ, ZSPLIT), THREADS, 0, stream>>>(
      x, w_mu, b_mu, w0_mu, b0_mu, out, wsf, counts, rowstart, order);
  finalize_kernel<<<1, 1, 0, stream>>>(wsf, out);
}